// Round 1
// baseline (2715.065 us; speedup 1.0000x reference)
//
#include <hip/hip_runtime.h>

typedef _Float16 f16x8 __attribute__((ext_vector_type(8)));
typedef _Float16 f16x4 __attribute__((ext_vector_type(4)));
typedef float f32x4 __attribute__((ext_vector_type(4)));

#define HID 4096
#define QDIM 6144
#define SEQ 2048
#define NH 32

// ---------------- LayerNorm: fp32 in -> f16 out ----------------
__global__ __launch_bounds__(256) void ln_k(const float* __restrict__ x,
    const float* __restrict__ w, const float* __restrict__ b,
    _Float16* __restrict__ out)
{
    __shared__ float red[8];
    const int tid = threadIdx.x;
    const int row = blockIdx.x;
    const float* xr = x + (size_t)row * HID;
    float4 v[4];
    float s = 0.f, ss = 0.f;
#pragma unroll
    for (int i = 0; i < 4; i++) {
        v[i] = ((const float4*)xr)[i * 256 + tid];
        s  += v[i].x + v[i].y + v[i].z + v[i].w;
        ss += v[i].x * v[i].x + v[i].y * v[i].y + v[i].z * v[i].z + v[i].w * v[i].w;
    }
#pragma unroll
    for (int o = 1; o < 64; o <<= 1) { s += __shfl_xor(s, o); ss += __shfl_xor(ss, o); }
    if ((tid & 63) == 0) { red[tid >> 6] = s; red[4 + (tid >> 6)] = ss; }
    __syncthreads();
    s  = red[0] + red[1] + red[2] + red[3];
    ss = red[4] + red[5] + red[6] + red[7];
    const float mu = s * (1.f / HID);
    const float rstd = rsqrtf(ss * (1.f / HID) - mu * mu + 1e-6f);
    _Float16* orow = out + (size_t)row * HID;
#pragma unroll
    for (int i = 0; i < 4; i++) {
        int base = (i * 256 + tid) * 4;
        float vv[4] = { v[i].x, v[i].y, v[i].z, v[i].w };
#pragma unroll
        for (int c = 0; c < 4; c++)
            orow[base + c] = (_Float16)((vv[c] - mu) * rstd * w[base + c] + b[base + c]);
    }
}

// ---------------- GEMM: C[2048,N] = A[2048,K](f16) * W[N,K](f32)^T ----------------
// 128x128 tile, BK=32, 4 waves in 2x2, each wave 64x64 (4x4 MFMA 16x16x32 f16).
// EPI: 0 = write f16, 1 = silu -> f16, 2 = resid + C -> f32
template<int EPI>
__global__ __launch_bounds__(256) void gemm_k(const _Float16* __restrict__ A,
    const float* __restrict__ W, int N, int K,
    _Float16* __restrict__ o16, const float* __restrict__ resid,
    float* __restrict__ of)
{
    __shared__ _Float16 As[128 * 40];
    __shared__ _Float16 Ws[128 * 40];
    const int tid  = threadIdx.x;
    const int lane = tid & 63, wid = tid >> 6;
    const int l15  = lane & 15, quad = lane >> 4;
    const int wr   = wid >> 1,  wc   = wid & 1;
    const int m0 = blockIdx.x * 128, n0 = blockIdx.y * 128;

    f32x4 acc[4][4] = {};
    for (int k0 = 0; k0 < K; k0 += 32) {
        __syncthreads();
        // stage A tile 128x32 (f16)
#pragma unroll
        for (int it = 0, c = tid; it < 2; it++, c += 256) {
            int row = c >> 2, col = (c & 3) << 3;
            f16x8 v = *(const f16x8*)(A + (size_t)(m0 + row) * K + k0 + col);
            *(f16x8*)(As + row * 40 + col) = v;
        }
        // stage W tile 128x32 (fp32 -> f16)
#pragma unroll
        for (int it = 0, c = tid; it < 4; it++, c += 256) {
            int row = c >> 3, col = (c & 7) << 2;
            float4 wv = *(const float4*)(W + (size_t)(n0 + row) * K + k0 + col);
            f16x4 hv = { (_Float16)wv.x, (_Float16)wv.y, (_Float16)wv.z, (_Float16)wv.w };
            *(f16x4*)(Ws + row * 40 + col) = hv;
        }
        __syncthreads();
        f16x8 a[4], b[4];
#pragma unroll
        for (int i = 0; i < 4; i++)
            a[i] = *(const f16x8*)(As + (wr * 64 + i * 16 + l15) * 40 + quad * 8);
#pragma unroll
        for (int j = 0; j < 4; j++)
            b[j] = *(const f16x8*)(Ws + (wc * 64 + j * 16 + l15) * 40 + quad * 8);
#pragma unroll
        for (int i = 0; i < 4; i++)
#pragma unroll
            for (int j = 0; j < 4; j++)
                acc[i][j] = __builtin_amdgcn_mfma_f32_16x16x32_f16(a[i], b[j], acc[i][j], 0, 0, 0);
    }
    // epilogue (C/D layout: row = quad*4 + r, col = l15)
#pragma unroll
    for (int i = 0; i < 4; i++) {
#pragma unroll
        for (int j = 0; j < 4; j++) {
#pragma unroll
            for (int r = 0; r < 4; r++) {
                int rg = m0 + wr * 64 + i * 16 + quad * 4 + r;
                int cg = n0 + wc * 64 + j * 16 + l15;
                size_t idx = (size_t)rg * N + cg;
                float cv = acc[i][j][r];
                if (EPI == 0)      o16[idx] = (_Float16)cv;
                else if (EPI == 1) o16[idx] = (_Float16)(cv / (1.f + __expf(-cv)));
                else               of[idx]  = resid[idx] + cv;
            }
        }
    }
}

// ---------------- RoPE + score-scale folding (in-place on f16 q,k) ----------------
__global__ __launch_bounds__(256) void rope_k(_Float16* __restrict__ q,
                                              _Float16* __restrict__ k)
{
    const int s = blockIdx.x, tid = threadIdx.x;
    _Float16* qr = q + (size_t)s * QDIM;
    _Float16* kr = k + (size_t)s * QDIM;
    const float scn = 0.08838834764831845f;   // 1/sqrt(128) folded into q_nope
#pragma unroll
    for (int it = 0, c = tid; it < 2; it++, c += 256) {
        f16x8 v = *(const f16x8*)(qr + c * 8);
#pragma unroll
        for (int e = 0; e < 8; e++) v[e] = (_Float16)((float)v[e] * scn);
        *(f16x8*)(qr + c * 8) = v;
    }
#pragma unroll
    for (int it = 0, c = tid; it < 4; it++, c += 256) {
        int hh = c >> 5, i = c & 31;
        float invf = exp2f(-(float)i * 0.41524101186092029f); // 10000^(-i/32)
        float ang = (float)s * invf;
        float co = cosf(ang), si = sinf(ang);
        int base = HID + hh * 64 + i;
        {
            float x1 = (float)qr[base], x2 = (float)qr[base + 32];
            qr[base]      = (_Float16)((x1 * co - x2 * si) * 0.125f); // 1/sqrt(64)
            qr[base + 32] = (_Float16)((x1 * si + x2 * co) * 0.125f);
        }
        {
            float x1 = (float)kr[base], x2 = (float)kr[base + 32];
            kr[base]      = (_Float16)(x1 * co - x2 * si);
            kr[base + 32] = (_Float16)(x1 * si + x2 * co);
        }
    }
}

// ---------------- Flash attention: 1 head x 64 q-rows per block ----------------
// 4 waves x 16 q-rows. BK=64. Online softmax. Causal mask analytic.
__global__ __launch_bounds__(256) void attn_k(const _Float16* __restrict__ qb,
    const _Float16* __restrict__ kb, const _Float16* __restrict__ vb,
    _Float16* __restrict__ ctxb)
{
    __shared__ _Float16 Ks[64 * 200];    // key-major, feat contiguous, pad to 200
    __shared__ _Float16 Vt[128 * 72];    // transposed: [d][k_local], pad to 72
    __shared__ _Float16 Ps[4][16 * 72];  // per-wave P transform buffer
    const int q0 = blockIdx.x * 64;
    const int h  = blockIdx.y;
    const int tid = threadIdx.x, lane = tid & 63, wid = tid >> 6;
    const int l15 = lane & 15, quad = lane >> 4;

    // Q fragments (A-layout): rows q0+wid*16+l15, feat = c*32 + quad*8 + j
    f16x8 aq[6];
    {
        const _Float16* qrow = qb + (size_t)(q0 + wid * 16 + l15) * QDIM;
#pragma unroll
        for (int c = 0; c < 6; c++) {
            int colb = (c < 4) ? (h * 128 + c * 32) : (HID + h * 64 + (c - 4) * 32);
            aq[c] = *(const f16x8*)(qrow + colb + quad * 8);
        }
    }
    f32x4 oacc[8] = {};
    float mrun[4] = { -1e30f, -1e30f, -1e30f, -1e30f };
    float lrun[4] = { 0.f, 0.f, 0.f, 0.f };

    const int nk = blockIdx.x + 1;
    for (int kt = 0; kt < nk; kt++) {
        const int k0 = kt * 64;
        __syncthreads();
        // stage K tile 64x192
        for (int c = tid; c < 1536; c += 256) {
            int f8 = c % 24, row = c / 24;
            int f = f8 << 3;
            int col = (f < 128) ? (h * 128 + f) : (HID + h * 64 + (f - 128));
            f16x8 v = *(const f16x8*)(kb + (size_t)(k0 + row) * QDIM + col);
            *(f16x8*)(Ks + row * 200 + f) = v;
        }
        // stage V tile transposed: Vt[d][kl]
        for (int c = tid; c < 1024; c += 256) {
            int kl = c & 63, d8 = c >> 6;
            f16x8 v = *(const f16x8*)(vb + (size_t)(k0 + kl) * HID + h * 128 + (d8 << 3));
#pragma unroll
            for (int e = 0; e < 8; e++) Vt[(d8 * 8 + e) * 72 + kl] = v[e];
        }
        __syncthreads();
        // S = Q K^T (4 key-subtiles of 16)
        f32x4 sa[4];
#pragma unroll
        for (int nt = 0; nt < 4; nt++) {
            f32x4 acc = {};
#pragma unroll
            for (int c = 0; c < 6; c++) {
                f16x8 bk = *(const f16x8*)(Ks + (nt * 16 + l15) * 200 + c * 32 + quad * 8);
                acc = __builtin_amdgcn_mfma_f32_16x16x32_f16(aq[c], bk, acc, 0, 0, 0);
            }
            sa[nt] = acc;
        }
        // online softmax per row (row = q0 + wid*16 + quad*4 + r; 16 cols per lane-group)
#pragma unroll
        for (int r = 0; r < 4; r++) {
            const int qrow = q0 + wid * 16 + quad * 4 + r;
            float mx = -1e30f;
#pragma unroll
            for (int nt = 0; nt < 4; nt++) {
                int kcol = k0 + nt * 16 + l15;
                float sv = (kcol <= qrow) ? sa[nt][r] : -1e30f;
                sa[nt][r] = sv;
                mx = fmaxf(mx, sv);
            }
#pragma unroll
            for (int o = 1; o < 16; o <<= 1) mx = fmaxf(mx, __shfl_xor(mx, o));
            float mnew = fmaxf(mrun[r], mx);
            float alpha = __expf(mrun[r] - mnew);
            mrun[r] = mnew;
            float sum = 0.f;
#pragma unroll
            for (int nt = 0; nt < 4; nt++) {
                float p = __expf(sa[nt][r] - mnew);
                sa[nt][r] = p;
                sum += p;
            }
#pragma unroll
            for (int o = 1; o < 16; o <<= 1) sum += __shfl_xor(sum, o);
            lrun[r] = lrun[r] * alpha + sum;
#pragma unroll
            for (int ot = 0; ot < 8; ot++) oacc[ot][r] *= alpha;
            // write P (C-layout) to LDS for A-layout reload
#pragma unroll
            for (int nt = 0; nt < 4; nt++)
                Ps[wid][(quad * 4 + r) * 72 + nt * 16 + l15] = (_Float16)sa[nt][r];
        }
        // O += P V
#pragma unroll
        for (int kc = 0; kc < 2; kc++) {
            f16x8 ap = *(const f16x8*)(&Ps[wid][l15 * 72 + kc * 32 + quad * 8]);
#pragma unroll
            for (int ot = 0; ot < 8; ot++) {
                f16x8 bv = *(const f16x8*)(Vt + (ot * 16 + l15) * 72 + kc * 32 + quad * 8);
                oacc[ot] = __builtin_amdgcn_mfma_f32_16x16x32_f16(ap, bv, oacc[ot], 0, 0, 0);
            }
        }
    }
    // normalize + write ctx (s, h*128 + d) as f16
#pragma unroll
    for (int r = 0; r < 4; r++) {
        const int srow = q0 + wid * 16 + quad * 4 + r;
        const float inv = 1.0f / lrun[r];
#pragma unroll
        for (int ot = 0; ot < 8; ot++)
            ctxb[(size_t)srow * HID + h * 128 + ot * 16 + l15] = (_Float16)(oacc[ot][r] * inv);
    }
}

extern "C" void kernel_launch(void* const* d_in, const int* in_sizes, int n_in,
                              void* d_out, int out_size, void* d_ws, size_t ws_size,
                              hipStream_t stream)
{
    const float* x   = (const float*)d_in[0];
    // d_in[1] = attention_mask (exactly causal -1e9; applied analytically)
    const float* wq  = (const float*)d_in[2];
    const float* wk  = (const float*)d_in[3];
    const float* wv  = (const float*)d_in[4];
    const float* wo  = (const float*)d_in[5];
    const float* l1w = (const float*)d_in[6];
    const float* l1b = (const float*)d_in[7];
    const float* l2w = (const float*)d_in[8];
    const float* l2b = (const float*)d_in[9];
    const float* w1  = (const float*)d_in[10];
    const float* w2  = (const float*)d_in[11];
    float* out = (float*)d_out;

    _Float16* ws   = (_Float16*)d_ws;
    _Float16* hb   = ws;                    // 2048*4096
    _Float16* qb   = ws + 8388608;          // 2048*6144
    _Float16* kb   = qb + 12582912;         // 2048*6144
    _Float16* vb   = kb + 12582912;         // 2048*4096
    _Float16* ctxb = vb + 8388608;          // 2048*4096
    _Float16* h2b  = hb;                    // reuse (hb dead after V gemm)
    _Float16* f1b  = qb;                    // reuse q/k/v region (dead after attn): 2048*16384

    ln_k<<<SEQ, 256, 0, stream>>>(x, l1w, l1b, hb);
    gemm_k<0><<<dim3(16, 48),  256, 0, stream>>>(hb, wq, QDIM, HID, qb, nullptr, nullptr);
    gemm_k<0><<<dim3(16, 48),  256, 0, stream>>>(hb, wk, QDIM, HID, kb, nullptr, nullptr);
    gemm_k<0><<<dim3(16, 32),  256, 0, stream>>>(hb, wv, HID,  HID, vb, nullptr, nullptr);
    rope_k<<<SEQ, 256, 0, stream>>>(qb, kb);
    attn_k<<<dim3(32, NH), 256, 0, stream>>>(qb, kb, vb, ctxb);
    gemm_k<2><<<dim3(16, 32),  256, 0, stream>>>(ctxb, wo, HID, HID, nullptr, x, out);
    ln_k<<<SEQ, 256, 0, stream>>>(out, l2w, l2b, h2b);
    gemm_k<1><<<dim3(16, 128), 256, 0, stream>>>(h2b, w1, 16384, HID, f1b, nullptr, nullptr);
    gemm_k<2><<<dim3(16, 32),  256, 0, stream>>>(f1b, w2, HID, 16384, nullptr, out, out);
}

// Round 2
// 2187.317 us; speedup vs baseline: 1.2413x; 1.2413x over previous
//
#include <hip/hip_runtime.h>

typedef _Float16 f16x8 __attribute__((ext_vector_type(8)));
typedef _Float16 f16x4 __attribute__((ext_vector_type(4)));
typedef float f32x4 __attribute__((ext_vector_type(4)));

#define HID 4096
#define SEQ 2048
#define NH 32
#define QKVS 16384   // fused qkv row stride: q[0,6144) k[6144,12288) v[12288,16384)

__device__ __forceinline__ void load_lds16(const void* g, void* l) {
    __builtin_amdgcn_global_load_lds((const __attribute__((address_space(1))) void*)g,
                                     (__attribute__((address_space(3))) void*)l, 16, 0, 0);
}

// ---------------- fp32 -> f16 weight conversion (pure BW) ----------------
__global__ __launch_bounds__(256) void conv_k(const float* __restrict__ s,
                                              _Float16* __restrict__ d)
{
    size_t i = ((size_t)blockIdx.x * 256 + threadIdx.x) * 8;
    float4 a = *(const float4*)(s + i);
    float4 b = *(const float4*)(s + i + 4);
    f16x8 o = { (_Float16)a.x, (_Float16)a.y, (_Float16)a.z, (_Float16)a.w,
                (_Float16)b.x, (_Float16)b.y, (_Float16)b.z, (_Float16)b.w };
    *(f16x8*)(d + i) = o;
}

// ---------------- LayerNorm: fp32 in -> f16 out ----------------
__global__ __launch_bounds__(256) void ln_k(const float* __restrict__ x,
    const float* __restrict__ w, const float* __restrict__ b,
    _Float16* __restrict__ out)
{
    __shared__ float red[8];
    const int tid = threadIdx.x;
    const int row = blockIdx.x;
    const float* xr = x + (size_t)row * HID;
    float4 v[4];
    float s = 0.f, ss = 0.f;
#pragma unroll
    for (int i = 0; i < 4; i++) {
        v[i] = ((const float4*)xr)[i * 256 + tid];
        s  += v[i].x + v[i].y + v[i].z + v[i].w;
        ss += v[i].x * v[i].x + v[i].y * v[i].y + v[i].z * v[i].z + v[i].w * v[i].w;
    }
#pragma unroll
    for (int o = 1; o < 64; o <<= 1) { s += __shfl_xor(s, o); ss += __shfl_xor(ss, o); }
    if ((tid & 63) == 0) { red[tid >> 6] = s; red[4 + (tid >> 6)] = ss; }
    __syncthreads();
    s  = red[0] + red[1] + red[2] + red[3];
    ss = red[4] + red[5] + red[6] + red[7];
    const float mu = s * (1.f / HID);
    const float rstd = rsqrtf(ss * (1.f / HID) - mu * mu + 1e-6f);
    _Float16* orow = out + (size_t)row * HID;
#pragma unroll
    for (int i = 0; i < 4; i++) {
        int base = (i * 256 + tid) * 4;
        float vv[4] = { v[i].x, v[i].y, v[i].z, v[i].w };
#pragma unroll
        for (int c = 0; c < 4; c++)
            orow[base + c] = (_Float16)((vv[c] - mu) * rstd * w[base + c] + b[base + c]);
    }
}

// ---------------- GEMM: C[2048,N] = A[2048,K](f16) * W[N,K]^T ----------------
// m97 structure: 128x128 tile, BK=64, global_load_lds(16B) staging, XOR-swizzled
// LDS, single buffer + 2 barriers, 4 waves 2x2, each 64x64 via 16x16x32 f16 MFMA.
// WF32: stage fp32 weights directly (fallback / no pre-convert), cvt at frag read.
// EPI: 0 = write f16 (ldc stride), 1 = silu -> f16, 2 = resid + C -> f32
template<int EPI, bool WF32>
__global__ __launch_bounds__(256) void gemm_k(const _Float16* __restrict__ A,
    const _Float16* __restrict__ W16, const float* __restrict__ W32,
    int N, int K, int ldc,
    _Float16* __restrict__ o16, const float* __restrict__ resid,
    float* __restrict__ of)
{
    __shared__ _Float16 As[128 * 64];
    __shared__ _Float16 Ws16[WF32 ? 8 : 128 * 64];
    __shared__ float    Ws32[WF32 ? 128 * 64 : 8];

    const int tid  = threadIdx.x;
    const int lane = tid & 63, wid = tid >> 6;
    const int l15  = lane & 15, quad = lane >> 4;
    const int wr   = wid >> 1,  wc   = wid & 1;

    // XCD-rectangle swizzle: xcd (assumed lin%8) owns 8 M-blocks x N/4 strips
    const int Nblk = gridDim.y;
    const int lin  = blockIdx.y * 16 + blockIdx.x;
    const int xcd  = lin & 7, sl = lin >> 3;
    const int mb   = (xcd >> 2) * 8 + (sl & 7);
    const int nb   = (xcd & 3) * (Nblk >> 2) + (sl >> 3);
    const int m0 = mb * 128, n0 = nb * 128;

    // staging lane geometry (f16 rows = 128B = 8 x 16B blocks)
    const int srow  = lane >> 3;                       // row within 8-row group
    const int sblk  = (lane & 7) ^ (srow & 7);         // XOR-swizzled source block
    const _Float16* gA = A + (size_t)(m0 + wid * 32 + srow) * K + sblk * 8;
    // f32 rows = 256B = 16 x 16B blocks
    const int srow32 = lane >> 4;
    const _Float16* gB16 = WF32 ? nullptr
        : W16 + (size_t)(n0 + wid * 32 + srow) * K + sblk * 8;

    f32x4 acc[4][4] = {};
    for (int k0 = 0; k0 < K; k0 += 64) {
        __syncthreads();
#pragma unroll
        for (int i = 0; i < 4; i++)
            load_lds16(gA + (size_t)i * 8 * K + k0, As + (wid * 32 + i * 8) * 64);
        if constexpr (!WF32) {
#pragma unroll
            for (int i = 0; i < 4; i++)
                load_lds16(gB16 + (size_t)i * 8 * K + k0, Ws16 + (wid * 32 + i * 8) * 64);
        } else {
#pragma unroll
            for (int i = 0; i < 8; i++) {
                int bg = (lane & 15) ^ (((i & 3) << 2) | srow32);
                const float* g = W32 + (size_t)(n0 + wid * 32 + i * 4 + srow32) * K + k0 + bg * 4;
                load_lds16(g, Ws32 + (wid * 32 + i * 4) * 64);
            }
        }
        __syncthreads();

        f16x8 a[2][4], b[2][4];
#pragma unroll
        for (int kk = 0; kk < 2; kk++)
#pragma unroll
            for (int i = 0; i < 4; i++)
                a[kk][i] = *(const f16x8*)(As + (wr * 64 + i * 16 + l15) * 64 +
                                           (((kk << 2) + quad) ^ (l15 & 7)) * 8);
#pragma unroll
        for (int kk = 0; kk < 2; kk++)
#pragma unroll
            for (int j = 0; j < 4; j++) {
                if constexpr (!WF32) {
                    b[kk][j] = *(const f16x8*)(Ws16 + (wc * 64 + j * 16 + l15) * 64 +
                                               (((kk << 2) + quad) ^ (l15 & 7)) * 8);
                } else {
                    const float* base = Ws32 + (wc * 64 + j * 16 + l15) * 64;
                    int p0 = ((kk << 2) + quad) << 1;
                    f32x4 w0 = *(const f32x4*)(base + ((p0 ^ l15) << 2));
                    f32x4 w1 = *(const f32x4*)(base + (((p0 + 1) ^ l15) << 2));
#pragma unroll
                    for (int e = 0; e < 4; e++) {
                        b[kk][j][e]     = (_Float16)w0[e];
                        b[kk][j][4 + e] = (_Float16)w1[e];
                    }
                }
            }
#pragma unroll
        for (int kk = 0; kk < 2; kk++)
#pragma unroll
            for (int i = 0; i < 4; i++)
#pragma unroll
                for (int j = 0; j < 4; j++)
                    acc[i][j] = __builtin_amdgcn_mfma_f32_16x16x32_f16(a[kk][i], b[kk][j], acc[i][j], 0, 0, 0);
    }

    // epilogue (C/D: row = quad*4 + r, col = l15)
#pragma unroll
    for (int i = 0; i < 4; i++)
#pragma unroll
        for (int j = 0; j < 4; j++)
#pragma unroll
            for (int r = 0; r < 4; r++) {
                int rg = m0 + wr * 64 + i * 16 + quad * 4 + r;
                int cg = n0 + wc * 64 + j * 16 + l15;
                size_t idx = (size_t)rg * ldc + cg;
                float cv = acc[i][j][r];
                if (EPI == 0)      o16[idx] = (_Float16)cv;
                else if (EPI == 1) o16[idx] = (_Float16)(cv / (1.f + __expf(-cv)));
                else               of[idx]  = resid[idx] + cv;
            }
}

// ---------------- RoPE + score-scale folding on fused qkv ----------------
__global__ __launch_bounds__(256) void rope_k(_Float16* __restrict__ qkv)
{
    const int s = blockIdx.x, tid = threadIdx.x;
    _Float16* row = qkv + (size_t)s * QKVS;
    const float scn = 0.08838834764831845f;   // 1/sqrt(128) folded into q_nope
#pragma unroll
    for (int it = 0, c = tid; it < 2; it++, c += 256) {
        f16x8 v = *(const f16x8*)(row + c * 8);
#pragma unroll
        for (int e = 0; e < 8; e++) v[e] = (_Float16)((float)v[e] * scn);
        *(f16x8*)(row + c * 8) = v;
    }
#pragma unroll
    for (int it = 0, c = tid; it < 4; it++, c += 256) {
        int hh = c >> 5, i = c & 31;
        float invf = exp2f(-(float)i * 0.41524101186092029f); // 10000^(-i/32)
        float ang = (float)s * invf;
        float co = cosf(ang), si = sinf(ang);
        int qb = 4096 + hh * 64 + i;
        int kb = 10240 + hh * 64 + i;
        {
            float x1 = (float)row[qb], x2 = (float)row[qb + 32];
            row[qb]      = (_Float16)((x1 * co - x2 * si) * 0.125f); // 1/sqrt(64)
            row[qb + 32] = (_Float16)((x1 * si + x2 * co) * 0.125f);
        }
        {
            float x1 = (float)row[kb], x2 = (float)row[kb + 32];
            row[kb]      = (_Float16)(x1 * co - x2 * si);
            row[kb + 32] = (_Float16)(x1 * si + x2 * co);
        }
    }
}

// ---------------- Flash attention on fused qkv ----------------
__global__ __launch_bounds__(256) void attn_k(const _Float16* __restrict__ qkv,
                                              _Float16* __restrict__ ctxb)
{
    __shared__ _Float16 Ks[64 * 200];
    __shared__ _Float16 Vt[128 * 72];
    __shared__ _Float16 Ps[4][16 * 72];
    const int q0 = blockIdx.x * 64;
    const int h  = blockIdx.y;
    const int tid = threadIdx.x, lane = tid & 63, wid = tid >> 6;
    const int l15 = lane & 15, quad = lane >> 4;
    const _Float16* qb = qkv;
    const _Float16* kb = qkv + 6144;
    const _Float16* vb = qkv + 12288;

    f16x8 aq[6];
    {
        const _Float16* qrow = qb + (size_t)(q0 + wid * 16 + l15) * QKVS;
#pragma unroll
        for (int c = 0; c < 6; c++) {
            int colb = (c < 4) ? (h * 128 + c * 32) : (4096 + h * 64 + (c - 4) * 32);
            aq[c] = *(const f16x8*)(qrow + colb + quad * 8);
        }
    }
    f32x4 oacc[8] = {};
    float mrun[4] = { -1e30f, -1e30f, -1e30f, -1e30f };
    float lrun[4] = { 0.f, 0.f, 0.f, 0.f };

    const int nk = blockIdx.x + 1;
    for (int kt = 0; kt < nk; kt++) {
        const int k0 = kt * 64;
        __syncthreads();
        for (int c = tid; c < 1536; c += 256) {
            int f8 = c % 24, r = c / 24;
            int f = f8 << 3;
            int col = (f < 128) ? (h * 128 + f) : (4096 + h * 64 + (f - 128));
            f16x8 v = *(const f16x8*)(kb + (size_t)(k0 + r) * QKVS + col);
            *(f16x8*)(Ks + r * 200 + f) = v;
        }
        for (int c = tid; c < 1024; c += 256) {
            int kl = c & 63, d8 = c >> 6;
            f16x8 v = *(const f16x8*)(vb + (size_t)(k0 + kl) * QKVS + h * 128 + (d8 << 3));
#pragma unroll
            for (int e = 0; e < 8; e++) Vt[(d8 * 8 + e) * 72 + kl] = v[e];
        }
        __syncthreads();
        f32x4 sa[4];
#pragma unroll
        for (int nt = 0; nt < 4; nt++) {
            f32x4 acc = {};
#pragma unroll
            for (int c = 0; c < 6; c++) {
                f16x8 bk = *(const f16x8*)(Ks + (nt * 16 + l15) * 200 + c * 32 + quad * 8);
                acc = __builtin_amdgcn_mfma_f32_16x16x32_f16(aq[c], bk, acc, 0, 0, 0);
            }
            sa[nt] = acc;
        }
#pragma unroll
        for (int r = 0; r < 4; r++) {
            const int qrow = q0 + wid * 16 + quad * 4 + r;
            float mx = -1e30f;
#pragma unroll
            for (int nt = 0; nt < 4; nt++) {
                int kcol = k0 + nt * 16 + l15;
                float sv = (kcol <= qrow) ? sa[nt][r] : -1e30f;
                sa[nt][r] = sv;
                mx = fmaxf(mx, sv);
            }
#pragma unroll
            for (int o = 1; o < 16; o <<= 1) mx = fmaxf(mx, __shfl_xor(mx, o));
            float mnew = fmaxf(mrun[r], mx);
            float alpha = __expf(mrun[r] - mnew);
            mrun[r] = mnew;
            float sum = 0.f;
#pragma unroll
            for (int nt = 0; nt < 4; nt++) {
                float p = __expf(sa[nt][r] - mnew);
                sa[nt][r] = p;
                sum += p;
            }
#pragma unroll
            for (int o = 1; o < 16; o <<= 1) sum += __shfl_xor(sum, o);
            lrun[r] = lrun[r] * alpha + sum;
#pragma unroll
            for (int ot = 0; ot < 8; ot++) oacc[ot][r] *= alpha;
#pragma unroll
            for (int nt = 0; nt < 4; nt++)
                Ps[wid][(quad * 4 + r) * 72 + nt * 16 + l15] = (_Float16)sa[nt][r];
        }
#pragma unroll
        for (int kc = 0; kc < 2; kc++) {
            f16x8 ap = *(const f16x8*)(&Ps[wid][l15 * 72 + kc * 32 + quad * 8]);
#pragma unroll
            for (int ot = 0; ot < 8; ot++) {
                f16x8 bv = *(const f16x8*)(Vt + (ot * 16 + l15) * 72 + kc * 32 + quad * 8);
                oacc[ot] = __builtin_amdgcn_mfma_f32_16x16x32_f16(ap, bv, oacc[ot], 0, 0, 0);
            }
        }
    }
#pragma unroll
    for (int r = 0; r < 4; r++) {
        const int srow = q0 + wid * 16 + quad * 4 + r;
        const float inv = 1.0f / lrun[r];
#pragma unroll
        for (int ot = 0; ot < 8; ot++)
            ctxb[(size_t)srow * HID + h * 128 + ot * 16 + l15] = (_Float16)(oacc[ot][r] * inv);
    }
}

extern "C" void kernel_launch(void* const* d_in, const int* in_sizes, int n_in,
                              void* d_out, int out_size, void* d_ws, size_t ws_size,
                              hipStream_t stream)
{
    const float* x   = (const float*)d_in[0];
    const float* wq  = (const float*)d_in[2];
    const float* wk  = (const float*)d_in[3];
    const float* wv  = (const float*)d_in[4];
    const float* wo  = (const float*)d_in[5];
    const float* l1w = (const float*)d_in[6];
    const float* l1b = (const float*)d_in[7];
    const float* l2w = (const float*)d_in[8];
    const float* l2b = (const float*)d_in[9];
    const float* w1  = (const float*)d_in[10];
    const float* w2  = (const float*)d_in[11];
    float* out = (float*)d_out;
    _Float16* ws = (_Float16*)d_ws;

    if (ws_size >= (size_t)268435456) {
        // Path A: pre-convert weights to f16, one reused 134MB buffer.
        _Float16* Wb   = ws;                 // 67,108,864 el (reused 3x)
        _Float16* Wo16 = ws + 67108864;      // 16,777,216 el
        _Float16* hb   = ws + 83886080;      // 8,388,608 el
        _Float16* qkvb = ws + 92274688;      // 33,554,432 el (reused as ffn1)
        _Float16* ctx  = ws + 125829120;     // 8,388,608 el

        conv_k<<<12288, 256, 0, stream>>>(wq, Wb);
        conv_k<<<12288, 256, 0, stream>>>(wk, Wb + 25165824);
        conv_k<<<8192,  256, 0, stream>>>(wv, Wb + 50331648);
        conv_k<<<8192,  256, 0, stream>>>(wo, Wo16);
        ln_k<<<SEQ, 256, 0, stream>>>(x, l1w, l1b, hb);
        gemm_k<0, false><<<dim3(16, 128), 256, 0, stream>>>(hb, Wb, nullptr, 16384, 4096, QKVS, qkvb, nullptr, nullptr);
        rope_k<<<SEQ, 256, 0, stream>>>(qkvb);
        attn_k<<<dim3(32, NH), 256, 0, stream>>>(qkvb, ctx);
        gemm_k<2, false><<<dim3(16, 32), 256, 0, stream>>>(ctx, Wo16, nullptr, 4096, 4096, 4096, nullptr, x, out);
        ln_k<<<SEQ, 256, 0, stream>>>(out, l2w, l2b, hb);
        conv_k<<<32768, 256, 0, stream>>>(w1, Wb);
        gemm_k<1, false><<<dim3(16, 128), 256, 0, stream>>>(hb, Wb, nullptr, 16384, 4096, QKVS, qkvb, nullptr, nullptr);
        conv_k<<<32768, 256, 0, stream>>>(w2, Wb);
        gemm_k<2, false><<<dim3(16, 32), 256, 0, stream>>>(qkvb, Wb, nullptr, 4096, 16384, 4096, nullptr, out, out);
    } else {
        // Path B: fp32 weights staged directly (100 MB footprint).
        _Float16* hb   = ws;                 // 8,388,608
        _Float16* qkvb = ws + 8388608;       // 33,554,432
        _Float16* ctx  = ws + 41943040;      // 8,388,608

        ln_k<<<SEQ, 256, 0, stream>>>(x, l1w, l1b, hb);
        gemm_k<0, true><<<dim3(16, 48), 256, 0, stream>>>(hb, nullptr, wq, 6144, 4096, QKVS, qkvb, nullptr, nullptr);
        gemm_k<0, true><<<dim3(16, 48), 256, 0, stream>>>(hb, nullptr, wk, 6144, 4096, QKVS, qkvb + 6144, nullptr, nullptr);
        gemm_k<0, true><<<dim3(16, 32), 256, 0, stream>>>(hb, nullptr, wv, 4096, 4096, QKVS, qkvb + 12288, nullptr, nullptr);
        rope_k<<<SEQ, 256, 0, stream>>>(qkvb);
        attn_k<<<dim3(32, NH), 256, 0, stream>>>(qkvb, ctx);
        gemm_k<2, true><<<dim3(16, 32), 256, 0, stream>>>(ctx, nullptr, wo, 4096, 4096, 4096, nullptr, x, out);
        ln_k<<<SEQ, 256, 0, stream>>>(out, l2w, l2b, hb);
        gemm_k<1, true><<<dim3(16, 128), 256, 0, stream>>>(hb, nullptr, w1, 16384, 4096, QKVS, qkvb, nullptr, nullptr);
        gemm_k<2, true><<<dim3(16, 32), 256, 0, stream>>>(qkvb, nullptr, w2, 4096, 16384, 4096, nullptr, out, out);
    }
}